// Round 12
// baseline (135.656 us; speedup 1.0000x reference)
//
#include <hip/hip_runtime.h>
#include <hip/hip_bf16.h>
#include <stdint.h>

typedef __attribute__((ext_vector_type(4))) float f32x4;
typedef __attribute__((ext_vector_type(8))) short s16x8;
typedef __attribute__((ext_vector_type(4))) unsigned int u32x4;

__device__ __forceinline__ void lut_entry(uint32_t by, uint32_t* r) {
    uint32_t r0 = 0, r1 = 0, r2 = 0, r3 = 0;
    if (by & 1)   r0 |= 0x3F80u;
    if (by & 2)   r0 |= 0x3F800000u;
    if (by & 4)   r1 |= 0x3F80u;
    if (by & 8)   r1 |= 0x3F800000u;
    if (by & 16)  r2 |= 0x3F80u;
    if (by & 32)  r2 |= 0x3F800000u;
    if (by & 64)  r3 |= 0x3F80u;
    if (by & 128) r3 |= 0x3F800000u;
    r[0] = r0; r[1] = r1; r[2] = r2; r[3] = r3;
}

// ONE kernel: encoder -> input GEMM -> recurrent LIF -> readout -> softmax.
// 64 blocks x 512 thr (8 waves); block owns 16 batch rows; wave w owns hidden
// cols [w*16, w*16+16). All spike-path arithmetic bitwise-identical to R11:
//  - encoder: same expressions, same feature->bit mapping (f -> word f>>5, bit f&31)
//  - I: same hi/lo MFMA chain (hi,lo per ks, ks ascending, single f32x4 acc);
//    D-layout (row fo*4+r, col n0+fr) == recur state layout, no transpose.
//  - rec: exact 3-way H/L/Q chain, ks ascending. c0 = (id + I_t) + rec.
__global__ __launch_bounds__(512, 1) void k_all(const float* __restrict__ x,
                                                const float* __restrict__ w_in,
                                                const float* __restrict__ w_rec,
                                                const float* __restrict__ w_actor,
                                                const float* __restrict__ w_critic,
                                                float* __restrict__ out) {
    __shared__ uint32_t lut[256][4];
    __shared__ uint32_t spkL[40][16][20];       // 16 words used, 20 for bank spread
    __shared__ __hip_bfloat16 rbh[32][136];     // 272B stride: 2-way banks, 16B aligned
    __shared__ __hip_bfloat16 rbl[32][136];
    __shared__ __align__(16) uint16_t zm16[2][16][8];
    __shared__ float smax[16][20];

    const int tid = threadIdx.x;
    const int lane = tid & 63, w = tid >> 6;    // 8 waves
    const int fr = lane & 15, fo = lane >> 4;
    const int n0 = w * 16;
    const int b0 = blockIdx.x * 16;

    if (tid < 256) lut_entry(tid, lut[tid]);
    if (tid < 128) ((uint16_t*)zm16)[tid] = 0;  // z_{-1} = 0

    // ---- actor/critic hi/lo split -> LDS (rows a>=19 zero) ----
    for (int idx = tid; idx < 32 * 128; idx += 512) {
        int a = idx >> 7, k = idx & 127;
        float f = (a < 18) ? w_actor[a * 128 + k] : ((a == 18) ? w_critic[k] : 0.f);
        __hip_bfloat16 hb = __float2bfloat16(f);
        rbh[a][k] = hb;
        rbl[a][k] = __float2bfloat16(f - __bfloat162float(hb));
    }

    // ---- encoder: thread = (row er, halfword eh) -> 16 neurons, all 40 steps ----
    {
        const int er = tid >> 5, eh = tid & 31;
        const float* xp = x + (size_t)(b0 + er) * 256 + (eh & 15) * 16;
        const float sgn = (eh < 16) ? 50.f : -50.f;
        float cur0,cur1,cur2,cur3,cur4,cur5,cur6,cur7,cur8,cur9,curA,curB,curC,curD,curE,curF;
        float4 x4;
        x4 = *(const float4*)(xp + 0);  cur0 = fmaxf(sgn*x4.x,0.f); cur1 = fmaxf(sgn*x4.y,0.f); cur2 = fmaxf(sgn*x4.z,0.f); cur3 = fmaxf(sgn*x4.w,0.f);
        x4 = *(const float4*)(xp + 4);  cur4 = fmaxf(sgn*x4.x,0.f); cur5 = fmaxf(sgn*x4.y,0.f); cur6 = fmaxf(sgn*x4.z,0.f); cur7 = fmaxf(sgn*x4.w,0.f);
        x4 = *(const float4*)(xp + 8);  cur8 = fmaxf(sgn*x4.x,0.f); cur9 = fmaxf(sgn*x4.y,0.f); curA = fmaxf(sgn*x4.z,0.f); curB = fmaxf(sgn*x4.w,0.f);
        x4 = *(const float4*)(xp + 12); curC = fmaxf(sgn*x4.x,0.f); curD = fmaxf(sgn*x4.y,0.f); curE = fmaxf(sgn*x4.z,0.f); curF = fmaxf(sgn*x4.w,0.f);
        float v0_=0,v1_=0,v2_=0,v3_=0,v4_=0,v5_=0,v6_=0,v7_=0,v8_=0,v9_=0,vA_=0,vB_=0,vC_=0,vD_=0,vE_=0,vF_=0;
        for (int t = 0; t < 40; ++t) {
            uint32_t bits = 0;
#define ENC(V, C, J) { V = V + 0.1f * (C - V); bool z = (V - 1.0f) > 0.f; \
                       if (z) { bits |= (1u << (J)); V = 0.f; } }
            ENC(v0_,cur0,0) ENC(v1_,cur1,1) ENC(v2_,cur2,2) ENC(v3_,cur3,3)
            ENC(v4_,cur4,4) ENC(v5_,cur5,5) ENC(v6_,cur6,6) ENC(v7_,cur7,7)
            ENC(v8_,cur8,8) ENC(v9_,cur9,9) ENC(vA_,curA,10) ENC(vB_,curB,11)
            ENC(vC_,curC,12) ENC(vD_,curD,13) ENC(vE_,curE,14) ENC(vF_,curF,15)
#undef ENC
            ((uint16_t*)&spkL[t][er][0])[eh] = (uint16_t)bits;
        }
    }

    // ---- w_in B-frags (in-register hi/lo split; col = n0+fr) ----
#define LOADB(i) s16x8 bh##i, bl##i; { \
    const float* p = w_in + (n0 + fr) * 512 + (i) * 32 + fo * 8; \
    f32x4 fa = *(const f32x4*)p; f32x4 fb = *(const f32x4*)(p + 4); \
    _Pragma("unroll") for (int j = 0; j < 8; ++j) { \
        float f = (j < 4) ? fa[j] : fb[j - 4]; \
        __hip_bfloat16 hb = __float2bfloat16(f); \
        float r1 = f - __bfloat162float(hb); \
        __hip_bfloat16 lb = __float2bfloat16(r1); \
        bh##i[j] = (short)*(unsigned short*)&hb; \
        bl##i[j] = (short)*(unsigned short*)&lb; } }
    LOADB(0)  LOADB(1)  LOADB(2)  LOADB(3)  LOADB(4)  LOADB(5)  LOADB(6)  LOADB(7)
    LOADB(8)  LOADB(9)  LOADB(10) LOADB(11) LOADB(12) LOADB(13) LOADB(14) LOADB(15)
#undef LOADB
    asm volatile("" : "+v"(bh0), "+v"(bh1), "+v"(bh2),  "+v"(bh3),
                      "+v"(bh4), "+v"(bh5), "+v"(bh6),  "+v"(bh7),
                      "+v"(bh8), "+v"(bh9), "+v"(bh10), "+v"(bh11),
                      "+v"(bh12),"+v"(bh13),"+v"(bh14), "+v"(bh15));
    asm volatile("" : "+v"(bl0), "+v"(bl1), "+v"(bl2),  "+v"(bl3),
                      "+v"(bl4), "+v"(bl5), "+v"(bl6),  "+v"(bl7),
                      "+v"(bl8), "+v"(bl9), "+v"(bl10), "+v"(bl11),
                      "+v"(bl12),"+v"(bl13),"+v"(bl14), "+v"(bl15));

    // ---- w_rec B-frags: exact 3-way split (hi+lo+lo2 == w bitwise) ----
#define LOADW(ks) s16x8 H##ks, L##ks, Q##ks; { \
    const float* p = w_rec + (n0 + fr) * 128 + (ks) * 32 + fo * 8; \
    _Pragma("unroll") for (int j = 0; j < 8; ++j) { \
        float f = p[j]; \
        __hip_bfloat16 hb = __float2bfloat16(f); \
        float r1 = f - __bfloat162float(hb); \
        __hip_bfloat16 lb = __float2bfloat16(r1); \
        float r2 = r1 - __bfloat162float(lb); \
        __hip_bfloat16 qb = __float2bfloat16(r2); \
        H##ks[j] = (short)*(unsigned short*)&hb; \
        L##ks[j] = (short)*(unsigned short*)&lb; \
        Q##ks[j] = (short)*(unsigned short*)&qb; } }
    LOADW(0) LOADW(1) LOADW(2) LOADW(3)
#undef LOADW
    asm volatile("" : "+v"(H0), "+v"(H1), "+v"(H2), "+v"(H3),
                      "+v"(L0), "+v"(L1), "+v"(L2), "+v"(L3),
                      "+v"(Q0), "+v"(Q1), "+v"(Q2), "+v"(Q3));

    __syncthreads();   // spikes + LDS weights ready

    // I-tile MFMA chain (identical to k_ingemm): 16 ks x (hi,lo), single acc
#define ICHAIN(dst, T_) { \
        u32x4 s0 = *(const u32x4*)&spkL[T_][fr][0]; \
        u32x4 s1 = *(const u32x4*)&spkL[T_][fr][4]; \
        u32x4 s2 = *(const u32x4*)&spkL[T_][fr][8]; \
        u32x4 s3 = *(const u32x4*)&spkL[T_][fr][12]; \
        f32x4 acc = (f32x4)0.f; \
        union { u32x4 u; s16x8 v; } cv; \
        uint32_t by; \
        _Pragma("unroll") for (int ks = 0; ks < 16; ++ks) { \
            uint32_t word = (ks < 4) ? s0[ks & 3] : (ks < 8) ? s1[ks & 3] \
                          : (ks < 12) ? s2[ks & 3] : s3[ks & 3]; \
            by = (word >> (fo * 8)) & 0xFFu; \
            cv.u = *(const u32x4*)lut[by]; \
            switch (ks) { \
            case 0:  acc = __builtin_amdgcn_mfma_f32_16x16x32_bf16(cv.v, bh0,  acc,0,0,0); acc = __builtin_amdgcn_mfma_f32_16x16x32_bf16(cv.v, bl0,  acc,0,0,0); break; \
            case 1:  acc = __builtin_amdgcn_mfma_f32_16x16x32_bf16(cv.v, bh1,  acc,0,0,0); acc = __builtin_amdgcn_mfma_f32_16x16x32_bf16(cv.v, bl1,  acc,0,0,0); break; \
            case 2:  acc = __builtin_amdgcn_mfma_f32_16x16x32_bf16(cv.v, bh2,  acc,0,0,0); acc = __builtin_amdgcn_mfma_f32_16x16x32_bf16(cv.v, bl2,  acc,0,0,0); break; \
            case 3:  acc = __builtin_amdgcn_mfma_f32_16x16x32_bf16(cv.v, bh3,  acc,0,0,0); acc = __builtin_amdgcn_mfma_f32_16x16x32_bf16(cv.v, bl3,  acc,0,0,0); break; \
            case 4:  acc = __builtin_amdgcn_mfma_f32_16x16x32_bf16(cv.v, bh4,  acc,0,0,0); acc = __builtin_amdgcn_mfma_f32_16x16x32_bf16(cv.v, bl4,  acc,0,0,0); break; \
            case 5:  acc = __builtin_amdgcn_mfma_f32_16x16x32_bf16(cv.v, bh5,  acc,0,0,0); acc = __builtin_amdgcn_mfma_f32_16x16x32_bf16(cv.v, bl5,  acc,0,0,0); break; \
            case 6:  acc = __builtin_amdgcn_mfma_f32_16x16x32_bf16(cv.v, bh6,  acc,0,0,0); acc = __builtin_amdgcn_mfma_f32_16x16x32_bf16(cv.v, bl6,  acc,0,0,0); break; \
            case 7:  acc = __builtin_amdgcn_mfma_f32_16x16x32_bf16(cv.v, bh7,  acc,0,0,0); acc = __builtin_amdgcn_mfma_f32_16x16x32_bf16(cv.v, bl7,  acc,0,0,0); break; \
            case 8:  acc = __builtin_amdgcn_mfma_f32_16x16x32_bf16(cv.v, bh8,  acc,0,0,0); acc = __builtin_amdgcn_mfma_f32_16x16x32_bf16(cv.v, bl8,  acc,0,0,0); break; \
            case 9:  acc = __builtin_amdgcn_mfma_f32_16x16x32_bf16(cv.v, bh9,  acc,0,0,0); acc = __builtin_amdgcn_mfma_f32_16x16x32_bf16(cv.v, bl9,  acc,0,0,0); break; \
            case 10: acc = __builtin_amdgcn_mfma_f32_16x16x32_bf16(cv.v, bh10, acc,0,0,0); acc = __builtin_amdgcn_mfma_f32_16x16x32_bf16(cv.v, bl10, acc,0,0,0); break; \
            case 11: acc = __builtin_amdgcn_mfma_f32_16x16x32_bf16(cv.v, bh11, acc,0,0,0); acc = __builtin_amdgcn_mfma_f32_16x16x32_bf16(cv.v, bl11, acc,0,0,0); break; \
            case 12: acc = __builtin_amdgcn_mfma_f32_16x16x32_bf16(cv.v, bh12, acc,0,0,0); acc = __builtin_amdgcn_mfma_f32_16x16x32_bf16(cv.v, bl12, acc,0,0,0); break; \
            case 13: acc = __builtin_amdgcn_mfma_f32_16x16x32_bf16(cv.v, bh13, acc,0,0,0); acc = __builtin_amdgcn_mfma_f32_16x16x32_bf16(cv.v, bl13, acc,0,0,0); break; \
            case 14: acc = __builtin_amdgcn_mfma_f32_16x16x32_bf16(cv.v, bh14, acc,0,0,0); acc = __builtin_amdgcn_mfma_f32_16x16x32_bf16(cv.v, bl14, acc,0,0,0); break; \
            default: acc = __builtin_amdgcn_mfma_f32_16x16x32_bf16(cv.v, bh15, acc,0,0,0); acc = __builtin_amdgcn_mfma_f32_16x16x32_bf16(cv.v, bl15, acc,0,0,0); break; \
            } \
        } \
        dst = acc; }

    f32x4 Icur;
    ICHAIN(Icur, 0)

    f32x4 v0 = (f32x4)0.f, c0 = (f32x4)0.f;
    f32x4 rva = (f32x4)0.f, ria = (f32x4)0.f, rma = (f32x4)(-1e30f);

    for (int t = 0; t < 40; ++t) {
        int tn = (t < 39) ? t + 1 : 39;

        // rec from z_{t-1}
        u32x4 zw = *(const u32x4*)zm16[t & 1][fr];
        union { u32x4 u; s16x8 v; } a0, a1, a2, a3;
        a0.u = *(const u32x4*)lut[(zw[0] >> (fo * 8)) & 0xFFu];
        a1.u = *(const u32x4*)lut[(zw[1] >> (fo * 8)) & 0xFFu];
        a2.u = *(const u32x4*)lut[(zw[2] >> (fo * 8)) & 0xFFu];
        a3.u = *(const u32x4*)lut[(zw[3] >> (fo * 8)) & 0xFFu];
        f32x4 r0 = (f32x4)0.f;
#define RECK(ks, av) \
        r0 = __builtin_amdgcn_mfma_f32_16x16x32_bf16(av, H##ks, r0, 0, 0, 0); \
        r0 = __builtin_amdgcn_mfma_f32_16x16x32_bf16(av, L##ks, r0, 0, 0, 0); \
        r0 = __builtin_amdgcn_mfma_f32_16x16x32_bf16(av, Q##ks, r0, 0, 0, 0);
        RECK(0, a0.v) RECK(1, a1.v) RECK(2, a2.v) RECK(3, a3.v)
#undef RECK

        // I for next step (independent of z -> overlaps rec)
        f32x4 Inxt;
        ICHAIN(Inxt, tn)

        // LIF update (verbatim expressions)
        f32x4 vd = v0 + 0.1f * (c0 - v0);
        f32x4 id = c0 - 0.2f * c0;
        unsigned long long B0, B1, B2, B3;
        bool z;
        z = (vd[0] - 1.0f) > 0.f; B0 = __ballot(z); if (z) vd[0] = 0.f;
        z = (vd[1] - 1.0f) > 0.f; B1 = __ballot(z); if (z) vd[1] = 0.f;
        z = (vd[2] - 1.0f) > 0.f; B2 = __ballot(z); if (z) vd[2] = 0.f;
        z = (vd[3] - 1.0f) > 0.f; B3 = __ballot(z); if (z) vd[3] = 0.f;
        v0 = vd;

        if (lane < 16) {
            int m = lane, rq = m & 3, sh = (m >> 2) * 16;
            unsigned long long s = (rq == 0) ? B0 : (rq == 1) ? B1 : (rq == 2) ? B2 : B3;
            zm16[(t & 1) ^ 1][m][w] = (uint16_t)((s >> sh) & 0xFFFFu);
        }

        c0 = (id + Icur) + r0;     // (i_dec + I_t) + rec
        Icur = Inxt;
        __syncthreads();

        // readout on waves 0,1 with z_t; B-frags streamed from LDS
        if (w < 2) {
            u32x4 zw2 = *(const u32x4*)zm16[(t & 1) ^ 1][fr];
            const int a_ch = w * 16 + fr;
            f32x4 racc = (f32x4)0.f;
#pragma unroll
            for (int ks = 0; ks < 4; ++ks) {
                uint32_t by = (zw2[ks] >> (fo * 8)) & 0xFFu;
                union { u32x4 u; s16x8 v; } cv;
                cv.u = *(const u32x4*)lut[by];
                s16x8 fh = *(const s16x8*)&rbh[a_ch][ks * 32 + fo * 8];
                s16x8 fl = *(const s16x8*)&rbl[a_ch][ks * 32 + fo * 8];
                racc = __builtin_amdgcn_mfma_f32_16x16x32_bf16(cv.v, fh, racc, 0, 0, 0);
                racc = __builtin_amdgcn_mfma_f32_16x16x32_bf16(cv.v, fl, racc, 0, 0, 0);
            }
            f32x4 nva = rva + 0.1f * (ria - rva);
            ria = ria - 0.2f * ria + racc;
            rva = nva;
#pragma unroll
            for (int r = 0; r < 4; ++r)
                rma[r] = fmaxf(rma[r], nva[r]);
        }
    }
#undef ICHAIN

    // gather maxima + softmax (verbatim R11)
    if (w == 0) {
#pragma unroll
        for (int r = 0; r < 4; ++r) smax[fo * 4 + r][fr] = rma[r];
    } else if (w == 1 && fr < 3) {
#pragma unroll
        for (int r = 0; r < 4; ++r) smax[fo * 4 + r][16 + fr] = rma[r];
    }
    __syncthreads();
    if (tid < 16) {
        int row = tid;
        float mx = -1e30f;
#pragma unroll
        for (int a2 = 0; a2 < 18; ++a2) mx = fmaxf(mx, smax[row][a2]);
        float s = 0.f;
#pragma unroll
        for (int a2 = 0; a2 < 18; ++a2) s += expf(smax[row][a2] - mx);
#pragma unroll
        for (int a2 = 0; a2 < 18; ++a2)
            out[(b0 + row) * 18 + a2] = expf(smax[row][a2] - mx) / s;
        out[18432 + b0 + row] = smax[row][18];
    }
}

extern "C" void kernel_launch(void* const* d_in, const int* in_sizes, int n_in,
                              void* d_out, int out_size, void* d_ws, size_t ws_size,
                              hipStream_t stream) {
    const float* x        = (const float*)d_in[0];
    const float* w_in     = (const float*)d_in[1];
    const float* w_rec    = (const float*)d_in[2];
    const float* w_actor  = (const float*)d_in[3];
    const float* w_critic = (const float*)d_in[4];
    float* out = (float*)d_out;
    (void)d_ws; (void)ws_size;

    hipLaunchKernelGGL(k_all, dim3(64), dim3(512), 0, stream,
                       x, w_in, w_rec, w_actor, w_critic, out);
}